// Round 7
// baseline (12650.690 us; speedup 1.0000x reference)
//
#include <hip/hip_runtime.h>

#define S_LEN 2048
#define HROW 264          // padded LDS row stride in f16
#define HBUF (16 * HROW)  // one 16-row tile buffer

typedef _Float16 f16;
typedef _Float16 f16x8 __attribute__((ext_vector_type(8)));
typedef float f32x4 __attribute__((ext_vector_type(4)));
typedef unsigned u32;
typedef unsigned long long u64;

#define PERM_SEL 0x05040100u  // perm(a,b,SEL) = lo16(b) | lo16(a)<<16

__device__ __forceinline__ float sigf(float x) {
  x = fminf(fmaxf(x, -30.f), 30.f);
  float e = __builtin_amdgcn_exp2f(-1.44269504089f * x);
  return __builtin_amdgcn_rcpf(1.f + e);
}
__device__ __forceinline__ float tanh_fast(float x) {
  x = fminf(fmaxf(x, -15.f), 15.f);
  float e = __builtin_amdgcn_exp2f(2.88539008178f * x);  // e^(2x)
  return 1.f - 2.f * __builtin_amdgcn_rcpf(e + 1.f);
}
__device__ __forceinline__ void st_hx(u32* p, u32 v) {
  __hip_atomic_store(p, v, __ATOMIC_RELAXED, __HIP_MEMORY_SCOPE_AGENT);
}
__device__ __forceinline__ u64 ld_hx64(const u64* p) {
  return __hip_atomic_load(p, __ATOMIC_RELAXED, __HIP_MEMORY_SCOPE_AGENT);
}
__device__ __forceinline__ u32 umin2(u32 a, u32 b) { return a < b ? a : b; }

// Build W16[1024][512] = [Whh | Wih] f16, bias = bih + bhh, zero hx tag words.
__global__ void convert_k(const float* __restrict__ Wih, const float* __restrict__ Whh,
                          const float* __restrict__ bih, const float* __restrict__ bhh,
                          f16* __restrict__ W16, float* __restrict__ bias,
                          u32* __restrict__ hx) {
  int i = blockIdx.x * blockDim.x + threadIdx.x;  // 524288 threads
  int n = i >> 9, k = i & 511;
  W16[i] = (f16)((k < 256) ? Whh[n * 256 + k] : Wih[n * 256 + (k - 256)]);
  if (i < 1024) bias[i] = bih[i] + bhh[i];
  if (i < 65536) hx[i] = 0u;  // 4 parity buffers; replay safety
}

// Pre-convert embedding table to f16 (8,192,000 elems, 8 per thread).
__global__ void convert_embed_k(const float* __restrict__ e, f16* __restrict__ e16) {
  int i = (blockIdx.x * 256 + threadIdx.x) * 8;
  float4 a = *(const float4*)(e + i);
  float4 b = *(const float4*)(e + i + 4);
  f16x8 v = {(f16)a.x, (f16)a.y, (f16)a.z, (f16)a.w,
             (f16)b.x, (f16)b.y, (f16)b.z, (f16)b.w};
  *(f16x8*)(e16 + i) = v;
}

// Persistent LSTM, 4 interleaved chains per wg (latency hiding of MALL RTT).
// 16 wgs = 4 gl-sets x 4 quarters (64 dims). Each wg runs 4 independent
// batch-groups (G = gl+4c, 4 batches each) packed into one M=16 tile:
// chain c owns D rows 4c..4c+3 and lanes kg==c for update/publish.
// x-part GEMM computed once for all 4 chains. h buffers per chain are zero
// outside the chain's rows, so h-MFMAs of different chains add disjointly.
// Exchange: tagged (tag<<16|f16) relaxed agent words, 4-deep parity;
// poll = 2 u64/lane. Per t: 4x{h-MFMA,update,publish,window} then 4x{poll,
// gather,barrier} -- every publish precedes every poll.
template <int EMB16>
__global__ __launch_bounds__(256, 1) void lstm_k(
    const f16* __restrict__ W16, const float* __restrict__ bias,
    const int* __restrict__ text, const float* __restrict__ embedf,
    const f16* __restrict__ embed16, const float* __restrict__ mask,
    float* __restrict__ out, u32* __restrict__ hx) {
  __shared__ __align__(16) f16 x_sw[4][HBUF];    // ring, rows = 4 chains x 4 batches
  __shared__ __align__(16) f16 h_all[8 * HBUF];  // [chain4][par2], zero outside rows

  const int tid = threadIdx.x;
  const int gl = blockIdx.x & 3;
  const int myq = blockIdx.x >> 2;

  const int wv = tid >> 6, l = tid & 63;
  const int kg = l >> 4, c16 = l & 15;
  const int jg = myq * 64 + wv * 16 + c16;  // this lane's dim (all 4 gates)

  // staging mapping: 16 rows x 16 threads x 16 dims
  const int srow = tid >> 4;
  const int spd = (tid & 15) * 16;
  const size_t strow = (size_t)((gl + 4 * (srow >> 2)) * 4 + (srow & 3)) * S_LEN;

  // poll mapping: wave pb polls batch pb; j<32 lanes take quarters {qa,qc}, else qb
  const int pb = tid >> 6, pj = tid & 63, pw = pj & 31;
  const int qa = 0 + (0 >= myq), qb = 1 + (1 >= myq), qc = 2 + (2 >= myq);
  const int pq1 = (pj < 32) ? qa : qb;
  const int pq2 = (pj < 32) ? qc : qb;

  // zero h_all (chain rows written later; other rows must stay 0)
  {
    f16x8 z = {(f16)0.f, (f16)0.f, (f16)0.f, (f16)0.f,
               (f16)0.f, (f16)0.f, (f16)0.f, (f16)0.f};
    for (int i = tid * 8; i < 8 * HBUF; i += 2048) *(f16x8*)&h_all[i] = z;
  }

  const float bi0 = bias[jg], bi1 = bias[256 + jg];
  const float bi2 = bias[512 + jg], bi3 = bias[768 + jg];

  float cc0[4] = {0.f, 0.f, 0.f, 0.f}, cc1[4] = {0.f, 0.f, 0.f, 0.f};
  float cc2[4] = {0.f, 0.f, 0.f, 0.f}, cc3[4] = {0.f, 0.f, 0.f, 0.f};
  float m0[4], m1[4], m2[4], m3[4];
#pragma unroll
  for (int i = 0; i < 4; i++) {
    if (kg == 0) m0[i] = mask[(size_t)((gl + 0) * 4 + i) * S_LEN];
    if (kg == 1) m1[i] = mask[(size_t)((gl + 4) * 4 + i) * S_LEN];
    if (kg == 2) m2[i] = mask[(size_t)((gl + 8) * 4 + i) * S_LEN];
    if (kg == 3) m3[i] = mask[(size_t)((gl + 12) * 4 + i) * S_LEN];
  }

  // resident W: barr[gate][kc], rows n = gate*256 + jg, k = kc*32 + kg*8
  f16x8 barr[4][16];
#pragma unroll
  for (int gg = 0; gg < 4; gg++) {
    const f16* w = W16 + (size_t)(gg * 256 + jg) * 512 + kg * 8;
#pragma unroll
    for (int kc = 0; kc < 16; kc++) barr[gg][kc] = *(const f16x8*)(w + kc * 32);
  }

  // x load helper (16 dims/thread)
  f16x8 sxa, sxb;
  int idx_r;
  auto ldx = [&](int idx, f16x8& o0, f16x8& o1) {
    if (EMB16) {
      const f16x8* ep = (const f16x8*)(embed16 + (size_t)idx * 256 + spd);
      o0 = ep[0];
      o1 = ep[1];
    } else {
      const float4* ep = (const float4*)(embedf + (size_t)idx * 256 + spd);
      float4 v0 = ep[0], v1 = ep[1], v2 = ep[2], v3 = ep[3];
      o0 = (f16x8){(f16)v0.x, (f16)v0.y, (f16)v0.z, (f16)v0.w,
                   (f16)v1.x, (f16)v1.y, (f16)v1.z, (f16)v1.w};
      o1 = (f16x8){(f16)v2.x, (f16)v2.y, (f16)v2.z, (f16)v2.w,
                   (f16)v3.x, (f16)v3.y, (f16)v3.z, (f16)v3.w};
    }
  };

  // x ring prologue: slots 0..3 = x[0..3]; sx = x[4]; idx_r = text[5]
#pragma unroll 1
  for (int pf = 0; pf < 4; pf++) {
    f16x8 h0, h1;
    ldx(text[strow + pf], h0, h1);
    *(f16x8*)&x_sw[pf][srow * HROW + spd] = h0;
    *(f16x8*)&x_sw[pf][srow * HROW + spd + 8] = h1;
  }
  ldx(text[strow + 4], sxa, sxb);
  idx_r = text[strow + 5];
  __syncthreads();

  f32x4 X0, X1, X2, X3;
  auto xpart = [&](int slot) {
    const f16* xs = &x_sw[slot][0];
    f32x4 t0 = {0.f, 0.f, 0.f, 0.f}, t1 = t0, t2 = t0, t3 = t0;
#pragma unroll
    for (int kc = 0; kc < 8; kc++) {
      f16x8 a = *(const f16x8*)&xs[c16 * HROW + kc * 32 + kg * 8];
      t0 = __builtin_amdgcn_mfma_f32_16x16x32_f16(a, barr[0][8 + kc], t0, 0, 0, 0);
      t1 = __builtin_amdgcn_mfma_f32_16x16x32_f16(a, barr[1][8 + kc], t1, 0, 0, 0);
      t2 = __builtin_amdgcn_mfma_f32_16x16x32_f16(a, barr[2][8 + kc], t2, 0, 0, 0);
      t3 = __builtin_amdgcn_mfma_f32_16x16x32_f16(a, barr[3][8 + kc], t3, 0, 0, 0);
    }
    X0 = t0; X1 = t1; X2 = t2; X3 = t3;
  };
  xpart(0);

  for (int t = 0; t < S_LEN; t++) {
    f32x4 a0 = X0, a1 = X1, a2 = X2, a3 = X3;  // shared acc, rows split by chain

    auto ph1 = [&](int c, int Gc, float (&cc)[4], float (&mm)[4]) {
      // h-part MFMA: h buffer zero outside chain c's rows -> adds only there
      const f16* hs = &h_all[(c * 2 + (t & 1)) * HBUF];
#pragma unroll
      for (int kc = 0; kc < 8; kc++) {
        f16x8 a = *(const f16x8*)&hs[c16 * HROW + kc * 32 + kg * 8];
        a0 = __builtin_amdgcn_mfma_f32_16x16x32_f16(a, barr[0][kc], a0, 0, 0, 0);
        a1 = __builtin_amdgcn_mfma_f32_16x16x32_f16(a, barr[1][kc], a1, 0, 0, 0);
        a2 = __builtin_amdgcn_mfma_f32_16x16x32_f16(a, barr[2][kc], a2, 0, 0, 0);
        a3 = __builtin_amdgcn_mfma_f32_16x16x32_f16(a, barr[3][kc], a3, 0, 0, 0);
      }
      f16* hd = &h_all[(c * 2 + ((t + 1) & 1)) * HBUF];
      if (kg == c) {  // D rows 4c..4c+3 live in these lanes
        const u32 tagv = (u32)(t + 1);
        u32* hb = hx + (size_t)((t + 1) & 3) * 16384 + Gc * 1024 + jg;
        float hv[4];
#pragma unroll
        for (int i = 0; i < 4; i++) {  // publish ASAP, ahead of HBM out-stores
          float gi = a0[i] + bi0, gf = a1[i] + bi1;
          float gG = a2[i] + bi2, go = a3[i] + bi3;
          cc[i] = sigf(gf) * cc[i] + sigf(gi) * tanh_fast(gG);
          hv[i] = sigf(go) * tanh_fast(cc[i]);
          st_hx(hb + i * 256, (tagv << 16) | (u32)__builtin_bit_cast(unsigned short, (f16)hv[i]));
        }
#pragma unroll
        for (int i = 0; i < 4; i++) {
          out[((size_t)(Gc * 4 + i) * S_LEN + t) * 256 + jg] = hv[i] * mm[i];
          hd[(c * 4 + i) * HROW + jg] = (f16)hv[i];
        }
        if (t + 1 < S_LEN) {
#pragma unroll
          for (int i = 0; i < 4; i++)
            mm[i] = mask[(size_t)(Gc * 4 + i) * S_LEN + (t + 1)];
        }
      }
      // shared window tasks (fill publish->poll gap; constant-folded per call)
      if (c == 0 && t + 4 < S_LEN) {
        *(f16x8*)&x_sw[t & 3][srow * HROW + spd] = sxa;
        *(f16x8*)&x_sw[t & 3][srow * HROW + spd + 8] = sxb;
      }
      if (c == 1 && t + 5 < S_LEN) ldx(idx_r, sxa, sxb);
      if (c == 2 && t + 6 < S_LEN) idx_r = text[strow + t + 6];
      if (c == 3 && t + 1 < S_LEN) xpart((t + 1) & 3);  // X for next step
    };

    auto ph2 = [&](int c, int Gc) {
      if (t + 1 < S_LEN) {
        const u32 expv = (u32)(t + 1);
        const u64* hb = (const u64*)hx + (size_t)((t + 1) & 3) * 8192 + Gc * 512 + pb * 128;
        u64 v1, v2;
        int done;
        do {
          v1 = ld_hx64(hb + pq1 * 32 + pw);
          v2 = ld_hx64(hb + pq2 * 32 + pw);
          u32 mn = umin2(umin2((u32)v1, (u32)(v1 >> 32)),
                         umin2((u32)v2, (u32)(v2 >> 32)));
          done = (int)((mn >> 16) == expv);
        } while (!__all(done));
        f16* hd = &h_all[(c * 2 + ((t + 1) & 1)) * HBUF];
        u32 p1 = __builtin_amdgcn_perm((u32)(v1 >> 32), (u32)v1, PERM_SEL);
        *(u32*)&hd[(c * 4 + pb) * HROW + pq1 * 64 + pw * 2] = p1;
        if (pj < 32) {
          u32 p2 = __builtin_amdgcn_perm((u32)(v2 >> 32), (u32)v2, PERM_SEL);
          *(u32*)&hd[(c * 4 + pb) * HROW + pq2 * 64 + pw * 2] = p2;
        }
      }
      __syncthreads();
    };

    ph1(0, gl, cc0, m0);
    ph1(1, gl + 4, cc1, m1);
    ph1(2, gl + 8, cc2, m2);
    ph1(3, gl + 12, cc3, m3);
    ph2(0, gl);
    ph2(1, gl + 4);
    ph2(2, gl + 8);
    ph2(3, gl + 12);
  }
}

extern "C" void kernel_launch(void* const* d_in, const int* in_sizes, int n_in,
                              void* d_out, int out_size, void* d_ws, size_t ws_size,
                              hipStream_t stream) {
  const int* text = (const int*)d_in[0];
  const float* mask = (const float*)d_in[1];
  // d_in[2] = len_seq: sort + inverse-sort is a no-op -> unused
  const float* embed = (const float*)d_in[3];
  const float* Wih = (const float*)d_in[4];
  const float* Whh = (const float*)d_in[5];
  const float* bih = (const float*)d_in[6];
  const float* bhh = (const float*)d_in[7];
  float* out = (float*)d_out;

  char* ws = (char*)d_ws;
  f16* W16 = (f16*)ws;                   // 1,048,576 B
  float* bias = (float*)(ws + 1048576);  // 4,096 B
  u32* hx = (u32*)(ws + 1052672);        // 262,144 B (4 parity x 16384 u32)
  f16* embed16 = (f16*)(ws + 1314816);   // 16,384,000 B
  const size_t WS_NEED = 1314816 + 16384000;

  convert_k<<<2048, 256, 0, stream>>>(Wih, Whh, bih, bhh, W16, bias, hx);
  if (ws_size >= WS_NEED) {
    convert_embed_k<<<4000, 256, 0, stream>>>(embed, embed16);
    lstm_k<1><<<16, 256, 0, stream>>>(W16, bias, text, embed, embed16, mask, out, hx);
  } else {
    lstm_k<0><<<16, 256, 0, stream>>>(W16, bias, text, embed, embed16, mask, out, hx);
  }
}